// Round 17
// baseline (223.816 us; speedup 1.0000x reference)
//
#include <hip/hip_runtime.h>
#include <math.h>

#define N_NODES 50000
#define N_EDGES 800000
#define HIDDEN  128
#define EDIM    32
#define NEG     0.2f

typedef __attribute__((ext_vector_type(8))) short bshort8;
typedef __attribute__((ext_vector_type(4))) float f32x4;

__device__ __forceinline__ unsigned short f2bf(float f) {
    unsigned u = __builtin_bit_cast(unsigned, f);
    return (unsigned short)((u + 0x7FFFu + ((u >> 16) & 1u)) >> 16);
}
__device__ __forceinline__ float bf2f(unsigned short b) {
    unsigned u = ((unsigned)b) << 16;
    return __builtin_bit_cast(float, u);
}

#define TILES_M (N_NODES / 16)                // 3125
#define GEMM_BLOCKS ((TILES_M + 3) / 4)       // 782
#define EB (N_EDGES / 256)                    // 3125
#define SCAN_BLOCKS ((N_NODES + 255) / 256)   // 196

// pipeline split: K1 = agg1 [0,X); K2 = agg1 [X,N) || gemm2 tiles [0,X/16)
#define X_SPLIT 35008
#define TILES_SPLIT (X_SPLIT / 16)            // 2188
#define AGG_B1 (X_SPLIT / 4)                  // 8752
#define AGG_B2 ((N_NODES - X_SPLIT) / 4)      // 3748
#define GEMM_B2 ((TILES_SPLIT + 3) / 4)       // 547
#define GEMM_B3 ((TILES_M - TILES_SPLIT + 3) / 4)  // 235

// ---------------------------------------------------------------------------
__device__ __forceinline__ void pack_w_body(int idx, const float* __restrict__ W,
                                            unsigned short* __restrict__ whp,
                                            unsigned short* __restrict__ wlp) {
    int e  = idx & 7;
    int l  = (idx >> 3) & 63;
    int kc = (idx >> 9) & 3;
    int ct = (idx >> 11);
    int k   = kc * 32 + ((l >> 4) << 3) + e;
    int col = ct * 16 + (l & 15);
    float w = W[k * HIDDEN + col];
    unsigned short hb = f2bf(w);
    whp[idx] = hb;
    wlp[idx] = f2bf(w - bf2f(hb));
}

// MFMA gemm tile: h = x @ W via bf16 split; one wave per 16-row tile.
// MODE 0: write h rows + alpha/beta scalars (layer 1).
// MODE 1: NO h write; write beta + pg = {alpha, g=h_row.Wl} (layer 2).
template<int MODE>
__device__ __forceinline__ void gemm_body(int tile, int t,
                                          const float* __restrict__ x,
                                          const unsigned short* __restrict__ wh,
                                          const unsigned short* __restrict__ wl,
                                          const float* __restrict__ a_s,
                                          const float* __restrict__ a_d,
                                          const float* __restrict__ gv,
                                          float* __restrict__ h,
                                          float* __restrict__ alpha,
                                          float* __restrict__ beta,
                                          float2* __restrict__ pg) {
    int l    = t & 63;
    int row0 = tile * 16;
    int arow = l & 15;
    int kg   = l >> 4;
    bshort8 ah[4], al[4];
    const float* xr = x + (size_t)(row0 + arow) * HIDDEN + (kg << 3);
#pragma unroll
    for (int kc = 0; kc < 4; kc++) {
        float4 f0 = *(const float4*)(xr + kc * 32);
        float4 f1 = *(const float4*)(xr + kc * 32 + 4);
        float fv[8] = {f0.x, f0.y, f0.z, f0.w, f1.x, f1.y, f1.z, f1.w};
#pragma unroll
        for (int e = 0; e < 8; e++) {
            unsigned short hb = f2bf(fv[e]);
            ah[kc][e] = (short)hb;
            al[kc][e] = (short)f2bf(fv[e] - bf2f(hb));
        }
    }
    float pal[4] = {0.f, 0.f, 0.f, 0.f};
    float pbe[4] = {0.f, 0.f, 0.f, 0.f};
    float pgl[4] = {0.f, 0.f, 0.f, 0.f};
#pragma unroll
    for (int ct = 0; ct < 8; ct++) {
        f32x4 acc = {0.f, 0.f, 0.f, 0.f};
#pragma unroll
        for (int kc = 0; kc < 4; kc++) {
            int fo = (((ct * 4 + kc) * 64) + l) << 3;
            bshort8 bh = *(const bshort8*)(wh + fo);
            bshort8 bl = *(const bshort8*)(wl + fo);
            acc = __builtin_amdgcn_mfma_f32_16x16x32_bf16(ah[kc], bh, acc, 0, 0, 0);
            acc = __builtin_amdgcn_mfma_f32_16x16x32_bf16(al[kc], bh, acc, 0, 0, 0);
            acc = __builtin_amdgcn_mfma_f32_16x16x32_bf16(ah[kc], bl, acc, 0, 0, 0);
        }
        int col = ct * 16 + arow;
        float a_sc = a_s[col], a_dc = a_d[col];
        float gvc = (MODE == 1) ? gv[col] : 0.f;
#pragma unroll
        for (int j = 0; j < 4; j++) {
            if (MODE == 0)
                h[(size_t)(row0 + kg * 4 + j) * HIDDEN + col] = acc[j];
            pal[j] += acc[j] * a_sc;
            pbe[j] += acc[j] * a_dc;
            if (MODE == 1) pgl[j] += acc[j] * gvc;
        }
    }
#pragma unroll
    for (int m = 1; m < 16; m <<= 1) {
#pragma unroll
        for (int j = 0; j < 4; j++) {
            pal[j] += __shfl_xor(pal[j], m, 64);
            pbe[j] += __shfl_xor(pbe[j], m, 64);
            if (MODE == 1) pgl[j] += __shfl_xor(pgl[j], m, 64);
        }
    }
    if (arow == 0) {
#pragma unroll
        for (int j = 0; j < 4; j++) {
            int r = row0 + kg * 4 + j;
            if (MODE == 0) {
                alpha[r] = pal[j];
                beta[r]  = pbe[j];
            } else {
                beta[r] = pbe[j];
                pg[r]   = make_float2(pal[j], pgl[j]);
            }
        }
    }
}

// Gather-aggregate body (layer 1, full 128-wide output).
__device__ __forceinline__ void agg_body(int i, int t,
                                         const int* __restrict__ off_work,
                                         const int* __restrict__ blockoff,
                                         const int* __restrict__ count,
                                         const float4* __restrict__ erec,
                                         const float* __restrict__ h,
                                         const float* __restrict__ alpha,
                                         const float* __restrict__ beta,
                                         const float* __restrict__ b,
                                         const float* __restrict__ part,
                                         float* __restrict__ outp) {
    int l = t & 63;
    float ps = part[l * 16];
#pragma unroll
    for (int m = 32; m > 0; m >>= 1) ps += __shfl_xor(ps, m, 64);
    float selfc = ps * (1.f / (float)N_EDGES);
    int start = off_work[i] + blockoff[i >> 8];
    int end   = start + count[i];
    float beta_i = beta[i];
    float2 acc = make_float2(0.f, 0.f);
    float wsum = 0.f;
    for (int cb = start; cb < end; cb += 64) {
        int n = min(64, end - cb);
        int sp = 0; float wt = 0.f;
        if (l < n) {
            float4 rec = erec[cb + l];
            sp = __float_as_int(rec.z);
            float lg = alpha[sp] + beta_i + rec.x;
            lg = lg > 0.f ? lg : NEG * lg;
            wt = expf(lg);
        }
        int j = 0;
        for (; j + 8 <= n; j += 8) {
            float w8[8]; int s8[8]; float2 h8[8];
#pragma unroll
            for (int q = 0; q < 8; q++) {
                w8[q] = __shfl(wt, j + q, 64);
                s8[q] = __shfl(sp, j + q, 64);
            }
#pragma unroll
            for (int q = 0; q < 8; q++)
                h8[q] = ((const float2*)(h + (size_t)s8[q] * HIDDEN))[l];
#pragma unroll
            for (int q = 0; q < 8; q++) {
                acc.x += w8[q] * h8[q].x;
                acc.y += w8[q] * h8[q].y;
                wsum  += w8[q];
            }
        }
        for (; j + 4 <= n; j += 4) {
            float w4[4]; int s4[4]; float2 h4[4];
#pragma unroll
            for (int q = 0; q < 4; q++) {
                w4[q] = __shfl(wt, j + q, 64);
                s4[q] = __shfl(sp, j + q, 64);
            }
#pragma unroll
            for (int q = 0; q < 4; q++)
                h4[q] = ((const float2*)(h + (size_t)s4[q] * HIDDEN))[l];
#pragma unroll
            for (int q = 0; q < 4; q++) {
                acc.x += w4[q] * h4[q].x;
                acc.y += w4[q] * h4[q].y;
                wsum  += w4[q];
            }
        }
        for (; j < n; j++) {
            float w = __shfl(wt, j, 64);
            int   sj = __shfl(sp, j, 64);
            float2 hv = ((const float2*)(h + (size_t)sj * HIDDEN))[l];
            acc.x += w * hv.x;
            acc.y += w * hv.y;
            wsum  += w;
        }
    }
    float lg = alpha[i] + beta_i + selfc;
    lg = lg > 0.f ? lg : NEG * lg;
    float exi = expf(lg);
    float denom = wsum + exi + 1e-16f;
    float2 hv = ((const float2*)(h + (size_t)i * HIDDEN))[l];
    float2 bb = ((const float2*)b)[l];
    float2 v;
    v.x = (acc.x + exi * hv.x) / denom + bb.x;
    v.y = (acc.y + exi * hv.y) / denom + bb.y;
    ((float2*)(outp + (size_t)i * HIDDEN))[l] =
        make_float2(fmaxf(v.x, 0.f), fmaxf(v.y, 0.f));
}

// ---------------------------------------------------------------------------
// FUSED prep: hist (EB) | pack W1 (64) | pack W2 (64) | consts + bldot (1)
__global__ void __launch_bounds__(256)
fused_prep_kernel(const int* __restrict__ dst, int* __restrict__ count,
                  int* __restrict__ rank,
                  const float* __restrict__ W1, unsigned short* __restrict__ whp1,
                  unsigned short* __restrict__ wlp1,
                  const float* __restrict__ W2, unsigned short* __restrict__ whp2,
                  unsigned short* __restrict__ wlp2,
                  const float* __restrict__ We1, const float* __restrict__ ae1,
                  const float* __restrict__ We2, const float* __restrict__ ae2,
                  const float* __restrict__ b2, const float* __restrict__ Wlin,
                  const float* __restrict__ bl, float* __restrict__ consts) {
    int b = blockIdx.x, t = threadIdx.x;
    if (b < EB) {
        int e = b * 256 + t;
        rank[e] = atomicAdd(&count[dst[e]], 1);
    } else if (b < EB + 64) {
        pack_w_body((b - EB) * 256 + t, W1, whp1, wlp1);
    } else if (b < EB + 128) {
        pack_w_body((b - EB - 64) * 256 + t, W2, whp2, wlp2);
    } else {
        if (t < 32) {
            float acc = 0.f;
            for (int k = 0; k < HIDDEN; k++) acc += We1[t * HIDDEN + k] * ae1[k];
            consts[t] = acc;
        } else if (t < 64) {
            int j = t - 32;
            float acc = 0.f;
            for (int k = 0; k < HIDDEN; k++) acc += We2[j * HIDDEN + k] * ae2[k];
            consts[32 + j] = acc;
        } else if (t < 128) {
            // wave 1: bldot = b2.Wl + bl
            int k = t - 64;
            float p = b2[k] * Wlin[k] + b2[k + 64] * Wlin[k + 64];
            for (int off = 32; off > 0; off >>= 1) p += __shfl_down(p, off, 64);
            if (t == 64) consts[64] = p + bl[0];
        }
    }
}

// ---------------------------------------------------------------------------
// 2-phase scan (blockoff folded into consumers)
__global__ void scan1_kernel(const int* __restrict__ count,
                             int* __restrict__ off_work, int* __restrict__ blocksum) {
    __shared__ int sh[256];
    int t = threadIdx.x;
    int idx = blockIdx.x * 256 + t;
    int v = (idx < N_NODES) ? count[idx] : 0;
    sh[t] = v;
    __syncthreads();
    for (int off = 1; off < 256; off <<= 1) {
        int u = (t >= off) ? sh[t - off] : 0;
        __syncthreads();
        sh[t] += u;
        __syncthreads();
    }
    if (idx < N_NODES) off_work[idx] = sh[t] - v;
    if (t == 255) blocksum[blockIdx.x] = sh[255];
}
__global__ void scan2_kernel(int* __restrict__ blocksum, int* __restrict__ blockoff) {
    __shared__ int sh[256];
    int t = threadIdx.x;
    int v = (t < SCAN_BLOCKS) ? blocksum[t] : 0;
    sh[t] = v;
    __syncthreads();
    for (int off = 1; off < 256; off <<= 1) {
        int u = (t >= off) ? sh[t - off] : 0;
        __syncthreads();
        sh[t] += u;
        __syncthreads();
    }
    if (t < SCAN_BLOCKS) blockoff[t] = sh[t] - v;
}

// ---------------------------------------------------------------------------
// Inverse-permutation build: einv[pos] = e.  4B random stores into a 3.2 MB
// table that is L2-resident per XCD -> lines merge before writeback.
__global__ void __launch_bounds__(256)
einv_kernel(const int* __restrict__ dst, const int* __restrict__ rank,
            const int* __restrict__ off_work, const int* __restrict__ blockoff,
            int* __restrict__ einv) {
    int e = blockIdx.x * 256 + threadIdx.x;
    int d = dst[e];
    int pos = off_work[d] + blockoff[d >> 8] + rank[e];
    einv[pos] = e;
}

// ---------------------------------------------------------------------------
// FUSED erec-pack (gather order: coalesced erec write, random-line ea read)
// + gemm1, 4:1 block-role interleave.
__global__ void __launch_bounds__(256)
fused_pack_gemm_kernel(const int* __restrict__ src,
                       const int* __restrict__ einv,
                       const float* __restrict__ ea,
                       const float* __restrict__ consts,
                       float4* __restrict__ erec, float* __restrict__ part,
                       const float* __restrict__ x,
                       const unsigned short* __restrict__ wh,
                       const unsigned short* __restrict__ wl,
                       const float* __restrict__ a_s, const float* __restrict__ a_d,
                       float* __restrict__ h, float* __restrict__ alpha,
                       float* __restrict__ beta) {
    __shared__ float cs[64];
    int b = blockIdx.x, t = threadIdx.x;
    bool is_gemm = ((b & 3) == 3) && ((b >> 2) < GEMM_BLOCKS);
    if (is_gemm) {
        int tile = (b >> 2) * 4 + (t >> 6);
        if (tile < TILES_M)
            gemm_body<0>(tile, t, x, wh, wl, a_s, a_d, nullptr, h, alpha, beta, nullptr);
        return;
    }
    int sid = b - min((b + 1) >> 2, GEMM_BLOCKS);
    if (t < 64) cs[t] = consts[t];
    __syncthreads();
    int p = sid * 256 + t;          // output position (coalesced)
    int e = einv[p];                // source edge (random, L2 3.2MB)
    const float4* ep = (const float4*)(ea + (size_t)e * EDIM);
    float d1 = 0.f, d2 = 0.f;
#pragma unroll
    for (int i = 0; i < 8; i++) {
        float4 v = ep[i];
        d1 += v.x * cs[4 * i] + v.y * cs[4 * i + 1] + v.z * cs[4 * i + 2] + v.w * cs[4 * i + 3];
        d2 += v.x * cs[32 + 4 * i] + v.y * cs[32 + 4 * i + 1] + v.z * cs[32 + 4 * i + 2] + v.w * cs[32 + 4 * i + 3];
    }
    erec[p] = make_float4(d1, d2, __int_as_float(src[e]), 0.f);
    float s1 = d1, s2 = d2;
    for (int off = 32; off > 0; off >>= 1) {
        s1 += __shfl_down(s1, off, 64);
        s2 += __shfl_down(s2, off, 64);
    }
    if ((t & 63) == 0) {
        int slot = (sid & 63) * 16;
        atomicAdd(&part[slot], s1);
        atomicAdd(&part[slot + 1], s2);
    }
}

// ---------------------------------------------------------------------------
// K1: agg1 on nodes [0, X_SPLIT)
__global__ void __launch_bounds__(256)
agg1_k1_kernel(const int* __restrict__ off_work, const int* __restrict__ blockoff,
               const int* __restrict__ count, const float4* __restrict__ erec,
               const float* __restrict__ h, const float* __restrict__ alpha,
               const float* __restrict__ beta, const float* __restrict__ b,
               const float* __restrict__ part, float* __restrict__ outp) {
    int i = blockIdx.x * 4 + (threadIdx.x >> 6);
    agg_body(i, threadIdx.x, off_work, blockoff, count, erec, h, alpha, beta,
             b, part, outp);
}

// K2: agg1 on nodes [X_SPLIT, N) || gemm2 tiles [0, TILES_SPLIT), 7:1 roles.
__global__ void __launch_bounds__(256)
fused_agg_gemm_kernel(const int* __restrict__ off_work, const int* __restrict__ blockoff,
                      const int* __restrict__ count, const float4* __restrict__ erec,
                      const float* __restrict__ h1, const float* __restrict__ alpha1,
                      const float* __restrict__ beta1, const float* __restrict__ b1,
                      const float* __restrict__ part, float* __restrict__ outB,
                      const float* __restrict__ Bx,
                      const unsigned short* __restrict__ wh2,
                      const unsigned short* __restrict__ wl2,
                      const float* __restrict__ as2, const float* __restrict__ ad2,
                      const float* __restrict__ Wlin,
                      float* __restrict__ beta2, float2* __restrict__ pg) {
    int b = blockIdx.x, t = threadIdx.x;
    bool is_gemm = ((b % 7) == 6) && ((b / 7) < GEMM_B2);
    if (is_gemm) {
        int tile = (b / 7) * 4 + (t >> 6);
        if (tile < TILES_SPLIT)
            gemm_body<1>(tile, t, Bx, wh2, wl2, as2, ad2, Wlin,
                         nullptr, nullptr, beta2, pg);
        return;
    }
    int sid = b - min((b + 1) / 7, GEMM_B2);
    int i = X_SPLIT + sid * 4 + (t >> 6);
    agg_body(i, t, off_work, blockoff, count, erec, h1, alpha1, beta1,
             b1, part, outB);
}

// K3: gemm2 remaining tiles
__global__ void __launch_bounds__(256)
gemm_k3_kernel(const float* __restrict__ Bx,
               const unsigned short* __restrict__ wh2,
               const unsigned short* __restrict__ wl2,
               const float* __restrict__ as2, const float* __restrict__ ad2,
               const float* __restrict__ Wlin,
               float* __restrict__ beta2, float2* __restrict__ pg) {
    int tile = TILES_SPLIT + blockIdx.x * 4 + (threadIdx.x >> 6);
    if (tile >= TILES_M) return;
    gemm_body<1>(tile, threadIdx.x, Bx, wh2, wl2, as2, ad2, Wlin,
                 nullptr, nullptr, beta2, pg);
}

// ---------------------------------------------------------------------------
// agg2-lite: out[i] = relu((Σ w·g[src] + exi·g[i])/denom + bldot)
__global__ void __launch_bounds__(256)
agg2_lite_kernel(const int* __restrict__ off_work, const int* __restrict__ blockoff,
                 const int* __restrict__ count, const float4* __restrict__ erec,
                 const float2* __restrict__ pg, const float* __restrict__ beta2,
                 const float* __restrict__ part, const float* __restrict__ consts,
                 float* __restrict__ out) {
    int t = threadIdx.x, l = t & 63;
    int i = blockIdx.x * 4 + (t >> 6);
    float ps = part[l * 16 + 1];
#pragma unroll
    for (int m = 32; m > 0; m >>= 1) ps += __shfl_xor(ps, m, 64);
    float selfc = ps * (1.f / (float)N_EDGES);
    int start = off_work[i] + blockoff[i >> 8];
    int end   = start + count[i];
    float beta_i = beta2[i];
    float wsum = 0.f, gsum = 0.f;
    for (int e = start + l; e < end; e += 64) {
        float4 rec = erec[e];
        int sp = __float_as_int(rec.z);
        float2 ag = pg[sp];
        float lg = ag.x + beta_i + rec.y;
        lg = lg > 0.f ? lg : NEG * lg;
        float w = expf(lg);
        wsum += w;
        gsum += w * ag.y;
    }
    for (int m = 32; m > 0; m >>= 1) {
        wsum += __shfl_xor(wsum, m, 64);
        gsum += __shfl_xor(gsum, m, 64);
    }
    if (l == 0) {
        float2 agi = pg[i];
        float lg = agi.x + beta_i + selfc;
        lg = lg > 0.f ? lg : NEG * lg;
        float exi = expf(lg);
        float denom = wsum + exi + 1e-16f;
        out[i] = fmaxf((gsum + exi * agi.y) / denom + consts[64], 0.f);
    }
}

// ---------------------------------------------------------------------------
extern "C" void kernel_launch(void* const* d_in, const int* in_sizes, int n_in,
                              void* d_out, int out_size, void* d_ws, size_t ws_size,
                              hipStream_t stream) {
    const float* x   = (const float*)d_in[0];
    const int*   src = (const int*)  d_in[1];
    const int*   dst = (const int*)  d_in[2];
    const float* ea  = (const float*)d_in[3];
    const float* W1  = (const float*)d_in[4];
    const float* We1 = (const float*)d_in[5];
    const float* as1 = (const float*)d_in[6];
    const float* ad1 = (const float*)d_in[7];
    const float* ae1 = (const float*)d_in[8];
    const float* b1  = (const float*)d_in[9];
    const float* W2  = (const float*)d_in[10];
    const float* We2 = (const float*)d_in[11];
    const float* as2 = (const float*)d_in[12];
    const float* ad2 = (const float*)d_in[13];
    const float* ae2 = (const float*)d_in[14];
    const float* b2  = (const float*)d_in[15];
    const float* Wl  = (const float*)d_in[16];
    const float* bl  = (const float*)d_in[17];
    float* out = (float*)d_out;

    float* ws      = (float*)d_ws;
    float* A       = ws;                           // [N*128] h1
    float* B       = A + (size_t)N_NODES * HIDDEN; // [N*128] conv1 out
    float4* erec   = (float4*)(B + (size_t)N_NODES * HIDDEN);  // [E] packed
    unsigned short* whp1 = (unsigned short*)(erec + N_EDGES);
    unsigned short* wlp1 = whp1 + 16384;
    unsigned short* whp2 = wlp1 + 16384;
    unsigned short* wlp2 = whp2 + 16384;
    float* alpha1  = (float*)(wlp2 + 16384);       // [N]
    float* beta1   = alpha1 + N_NODES;             // [N]
    float* beta2   = beta1 + N_NODES;              // [N]
    float2* pg     = (float2*)(beta2 + N_NODES);   // [N] {alpha2, g}
    float* consts  = (float*)(pg + N_NODES);       // [80]
    float* part    = consts + 80;                  // [64*16]
    int* count     = (int*)(part + 64 * 16);       // [N]
    int* off_work  = count + N_NODES;              // [N]
    int* blocksum  = off_work + N_NODES;           // [SCAN_BLOCKS]
    int* blockoff  = blocksum + SCAN_BLOCKS;       // [SCAN_BLOCKS]
    int* rank      = blockoff + SCAN_BLOCKS;       // [E]
    int* einv      = rank + N_EDGES;               // [E] pos -> edge

    // ---- prep ----
    hipMemsetAsync(count, 0, N_NODES * sizeof(int), stream);
    hipMemsetAsync(part, 0, 64 * 16 * sizeof(float), stream);
    fused_prep_kernel<<<EB + 129, 256, 0, stream>>>(dst, count, rank,
                                                    W1, whp1, wlp1, W2, whp2, wlp2,
                                                    We1, ae1, We2, ae2,
                                                    b2, Wl, bl, consts);
    scan1_kernel<<<SCAN_BLOCKS, 256, 0, stream>>>(count, off_work, blocksum);
    scan2_kernel<<<1, 256, 0, stream>>>(blocksum, blockoff);
    einv_kernel<<<EB, 256, 0, stream>>>(dst, rank, off_work, blockoff, einv);

    // ---- erec pack (gather order) + gemm1 (h1 -> A, alpha1/beta1) ----
    fused_pack_gemm_kernel<<<EB + GEMM_BLOCKS, 256, 0, stream>>>(
        src, einv, ea, consts, erec, part,
        x, whp1, wlp1, as1, ad1, A, alpha1, beta1);

    // ---- pipelined agg1 / gemm2 ----
    agg1_k1_kernel<<<AGG_B1, 256, 0, stream>>>(off_work, blockoff, count, erec,
                                               A, alpha1, beta1, b1, part, B);
    fused_agg_gemm_kernel<<<AGG_B2 + GEMM_B2, 256, 0, stream>>>(
        off_work, blockoff, count, erec, A, alpha1, beta1, b1, part, B,
        B, whp2, wlp2, as2, ad2, Wl, beta2, pg);
    gemm_k3_kernel<<<GEMM_B3, 256, 0, stream>>>(B, whp2, wlp2, as2, ad2,
                                                Wl, beta2, pg);

    // ---- conv2 aggregate + final linear (scalar form) ----
    agg2_lite_kernel<<<N_NODES / 4, 256, 0, stream>>>(off_work, blockoff, count,
                                                      erec, pg, beta2, part,
                                                      consts, out);
}

// Round 18
// 185.899 us; speedup vs baseline: 1.2040x; 1.2040x over previous
//
#include <hip/hip_runtime.h>
#include <math.h>

#define N_NODES 50000
#define N_EDGES 800000
#define HIDDEN  128
#define EDIM    32
#define NEG     0.2f

typedef __attribute__((ext_vector_type(8))) short bshort8;
typedef __attribute__((ext_vector_type(4))) float f32x4;

__device__ __forceinline__ unsigned short f2bf(float f) {
    unsigned u = __builtin_bit_cast(unsigned, f);
    return (unsigned short)((u + 0x7FFFu + ((u >> 16) & 1u)) >> 16);
}
__device__ __forceinline__ float bf2f(unsigned short b) {
    unsigned u = ((unsigned)b) << 16;
    return __builtin_bit_cast(float, u);
}

#define TILES_M (N_NODES / 16)                // 3125
#define GEMM_BLOCKS ((TILES_M + 3) / 4)       // 782
#define EB (N_EDGES / 256)                    // 3125
#define SCAN_BLOCKS ((N_NODES + 255) / 256)   // 196

// consts layout: [0:32) ce1 | [32:64) ce2 | [64] bldot |
//                [128:256) u=W2@Wl | [256:384) va=W2@as2 | [384:512) vb=W2@ad2
// ---------------------------------------------------------------------------
__device__ __forceinline__ void pack_w_body(int idx, const float* __restrict__ W,
                                            unsigned short* __restrict__ whp,
                                            unsigned short* __restrict__ wlp) {
    int e  = idx & 7;
    int l  = (idx >> 3) & 63;
    int kc = (idx >> 9) & 3;
    int ct = (idx >> 11);
    int k   = kc * 32 + ((l >> 4) << 3) + e;
    int col = ct * 16 + (l & 15);
    float w = W[k * HIDDEN + col];
    unsigned short hb = f2bf(w);
    whp[idx] = hb;
    wlp[idx] = f2bf(w - bf2f(hb));
}

// MFMA gemm tile (layer 1): h = x @ W via bf16 split; one wave/16-row tile.
__device__ __forceinline__ void gemm_body(int tile, int t,
                                          const float* __restrict__ x,
                                          const unsigned short* __restrict__ wh,
                                          const unsigned short* __restrict__ wl,
                                          const float* __restrict__ a_s,
                                          const float* __restrict__ a_d,
                                          float* __restrict__ h,
                                          float* __restrict__ alpha,
                                          float* __restrict__ beta) {
    int l    = t & 63;
    int row0 = tile * 16;
    int arow = l & 15;
    int kg   = l >> 4;
    bshort8 ah[4], al[4];
    const float* xr = x + (size_t)(row0 + arow) * HIDDEN + (kg << 3);
#pragma unroll
    for (int kc = 0; kc < 4; kc++) {
        float4 f0 = *(const float4*)(xr + kc * 32);
        float4 f1 = *(const float4*)(xr + kc * 32 + 4);
        float fv[8] = {f0.x, f0.y, f0.z, f0.w, f1.x, f1.y, f1.z, f1.w};
#pragma unroll
        for (int e = 0; e < 8; e++) {
            unsigned short hb = f2bf(fv[e]);
            ah[kc][e] = (short)hb;
            al[kc][e] = (short)f2bf(fv[e] - bf2f(hb));
        }
    }
    float pal[4] = {0.f, 0.f, 0.f, 0.f};
    float pbe[4] = {0.f, 0.f, 0.f, 0.f};
#pragma unroll
    for (int ct = 0; ct < 8; ct++) {
        f32x4 acc = {0.f, 0.f, 0.f, 0.f};
#pragma unroll
        for (int kc = 0; kc < 4; kc++) {
            int fo = (((ct * 4 + kc) * 64) + l) << 3;
            bshort8 bh = *(const bshort8*)(wh + fo);
            bshort8 bl = *(const bshort8*)(wl + fo);
            acc = __builtin_amdgcn_mfma_f32_16x16x32_bf16(ah[kc], bh, acc, 0, 0, 0);
            acc = __builtin_amdgcn_mfma_f32_16x16x32_bf16(al[kc], bh, acc, 0, 0, 0);
            acc = __builtin_amdgcn_mfma_f32_16x16x32_bf16(ah[kc], bl, acc, 0, 0, 0);
        }
        int col = ct * 16 + arow;
        float a_sc = a_s[col], a_dc = a_d[col];
#pragma unroll
        for (int j = 0; j < 4; j++) {
            h[(size_t)(row0 + kg * 4 + j) * HIDDEN + col] = acc[j];
            pal[j] += acc[j] * a_sc;
            pbe[j] += acc[j] * a_dc;
        }
    }
#pragma unroll
    for (int m = 1; m < 16; m <<= 1) {
#pragma unroll
        for (int j = 0; j < 4; j++) {
            pal[j] += __shfl_xor(pal[j], m, 64);
            pbe[j] += __shfl_xor(pbe[j], m, 64);
        }
    }
    if (arow == 0) {
#pragma unroll
        for (int j = 0; j < 4; j++) {
            alpha[row0 + kg * 4 + j] = pal[j];
            beta[row0 + kg * 4 + j]  = pbe[j];
        }
    }
}

// ---------------------------------------------------------------------------
// FUSED prep: hist (EB) | pack W1 (64) | consts+bldot (1) | u/va/vb matvecs (1)
__global__ void __launch_bounds__(256)
fused_prep_kernel(const int* __restrict__ dst, int* __restrict__ count,
                  int* __restrict__ rank,
                  const float* __restrict__ W1, unsigned short* __restrict__ whp1,
                  unsigned short* __restrict__ wlp1,
                  const float* __restrict__ We1, const float* __restrict__ ae1,
                  const float* __restrict__ We2, const float* __restrict__ ae2,
                  const float* __restrict__ W2,
                  const float* __restrict__ as2, const float* __restrict__ ad2,
                  const float* __restrict__ b2, const float* __restrict__ Wlin,
                  const float* __restrict__ bl, float* __restrict__ consts) {
    int b = blockIdx.x, t = threadIdx.x;
    if (b < EB) {
        int e = b * 256 + t;
        rank[e] = atomicAdd(&count[dst[e]], 1);
    } else if (b < EB + 64) {
        pack_w_body((b - EB) * 256 + t, W1, whp1, wlp1);
    } else if (b == EB + 64) {
        if (t < 32) {
            float acc = 0.f;
            for (int k = 0; k < HIDDEN; k++) acc += We1[t * HIDDEN + k] * ae1[k];
            consts[t] = acc;
        } else if (t < 64) {
            int j = t - 32;
            float acc = 0.f;
            for (int k = 0; k < HIDDEN; k++) acc += We2[j * HIDDEN + k] * ae2[k];
            consts[32 + j] = acc;
        } else if (t < 128) {
            // bldot = b2.Wl + bl
            int k = t - 64;
            float p = b2[k] * Wlin[k] + b2[k + 64] * Wlin[k + 64];
            for (int off = 32; off > 0; off >>= 1) p += __shfl_down(p, off, 64);
            if (t == 64) consts[64] = p + bl[0];
        }
    } else {
        // u[c]=W2[c,:].Wl ; va[c]=W2[c,:].as2 ; vb[c]=W2[c,:].ad2
        if (t < HIDDEN) {
            const float* wr = W2 + (size_t)t * HIDDEN;
            float su = 0.f, sa = 0.f, sb = 0.f;
            for (int k = 0; k < HIDDEN; k++) {
                float w = wr[k];
                su += w * Wlin[k];
                sa += w * as2[k];
                sb += w * ad2[k];
            }
            consts[128 + t] = su;
            consts[256 + t] = sa;
            consts[384 + t] = sb;
        }
    }
}

// ---------------------------------------------------------------------------
// 2-phase scan (blockoff folded into consumers)
__global__ void scan1_kernel(const int* __restrict__ count,
                             int* __restrict__ off_work, int* __restrict__ blocksum) {
    __shared__ int sh[256];
    int t = threadIdx.x;
    int idx = blockIdx.x * 256 + t;
    int v = (idx < N_NODES) ? count[idx] : 0;
    sh[t] = v;
    __syncthreads();
    for (int off = 1; off < 256; off <<= 1) {
        int u = (t >= off) ? sh[t - off] : 0;
        __syncthreads();
        sh[t] += u;
        __syncthreads();
    }
    if (idx < N_NODES) off_work[idx] = sh[t] - v;
    if (t == 255) blocksum[blockIdx.x] = sh[255];
}
__global__ void scan2_kernel(int* __restrict__ blocksum, int* __restrict__ blockoff) {
    __shared__ int sh[256];
    int t = threadIdx.x;
    int v = (t < SCAN_BLOCKS) ? blocksum[t] : 0;
    sh[t] = v;
    __syncthreads();
    for (int off = 1; off < 256; off <<= 1) {
        int u = (t >= off) ? sh[t - off] : 0;
        __syncthreads();
        sh[t] += u;
        __syncthreads();
    }
    if (t < SCAN_BLOCKS) blockoff[t] = sh[t] - v;
}

// ---------------------------------------------------------------------------
// FUSED scatter_dotv + gemm1, 4:1 block-role interleave (R16 structure).
__global__ void __launch_bounds__(256)
fused_scatter_gemm_kernel(const int* __restrict__ src, const int* __restrict__ dst,
                          const int* __restrict__ rank,
                          const float* __restrict__ ea,
                          const float* __restrict__ consts,
                          const int* __restrict__ off_work,
                          const int* __restrict__ blockoff,
                          float4* __restrict__ erec, float* __restrict__ part,
                          const float* __restrict__ x,
                          const unsigned short* __restrict__ wh,
                          const unsigned short* __restrict__ wl,
                          const float* __restrict__ a_s, const float* __restrict__ a_d,
                          float* __restrict__ h, float* __restrict__ alpha,
                          float* __restrict__ beta) {
    __shared__ float cs[64];
    int b = blockIdx.x, t = threadIdx.x;
    bool is_gemm = ((b & 3) == 3) && ((b >> 2) < GEMM_BLOCKS);
    if (is_gemm) {
        int tile = (b >> 2) * 4 + (t >> 6);
        if (tile < TILES_M)
            gemm_body(tile, t, x, wh, wl, a_s, a_d, h, alpha, beta);
        return;
    }
    int sid = b - min((b + 1) >> 2, GEMM_BLOCKS);
    if (t < 64) cs[t] = consts[t];
    __syncthreads();
    int e = sid * 256 + t;
    const float4* ep = (const float4*)(ea + (size_t)e * EDIM);
    float d1 = 0.f, d2 = 0.f;
#pragma unroll
    for (int i = 0; i < 8; i++) {
        float4 v = ep[i];
        d1 += v.x * cs[4 * i] + v.y * cs[4 * i + 1] + v.z * cs[4 * i + 2] + v.w * cs[4 * i + 3];
        d2 += v.x * cs[32 + 4 * i] + v.y * cs[32 + 4 * i + 1] + v.z * cs[32 + 4 * i + 2] + v.w * cs[32 + 4 * i + 3];
    }
    int d = dst[e];
    int pos = off_work[d] + blockoff[d >> 8] + rank[e];
    erec[pos] = make_float4(d1, d2, __int_as_float(src[e]), 0.f);
    float s1 = d1, s2 = d2;
    for (int off = 32; off > 0; off >>= 1) {
        s1 += __shfl_down(s1, off, 64);
        s2 += __shfl_down(s2, off, 64);
    }
    if ((t & 63) == 0) {
        int slot = (sid & 63) * 16;
        atomicAdd(&part[slot], s1);
        atomicAdd(&part[slot + 1], s2);
    }
}

// ---------------------------------------------------------------------------
// agg1: gather-aggregate conv1 (one wave/node), then fold conv2's GEMM into
// the epilogue: B-row never written; instead emit beta2[i]=B.vb,
// pg[i]={B.va, B.u}  (u/va/vb are W2-projected vectors from prep).
__global__ void __launch_bounds__(256)
agg1_kernel(const int* __restrict__ off_work, const int* __restrict__ blockoff,
            const int* __restrict__ count, const float4* __restrict__ erec,
            const float* __restrict__ h,
            const float* __restrict__ alpha, const float* __restrict__ beta,
            const float* __restrict__ b, const float* __restrict__ part,
            const float* __restrict__ consts,
            float* __restrict__ beta2, float2* __restrict__ pg) {
    int t = threadIdx.x;
    int l = t & 63;
    int i = blockIdx.x * 4 + (t >> 6);
    float ps = part[l * 16];
#pragma unroll
    for (int m = 32; m > 0; m >>= 1) ps += __shfl_xor(ps, m, 64);
    float selfc = ps * (1.f / (float)N_EDGES);
    int start = off_work[i] + blockoff[i >> 8];
    int end   = start + count[i];
    float beta_i = beta[i];
    float2 acc = make_float2(0.f, 0.f);
    float wsum = 0.f;
    for (int cb = start; cb < end; cb += 64) {
        int n = min(64, end - cb);
        int sp = 0; float wt = 0.f;
        if (l < n) {
            float4 rec = erec[cb + l];
            sp = __float_as_int(rec.z);
            float lg = alpha[sp] + beta_i + rec.x;
            lg = lg > 0.f ? lg : NEG * lg;
            wt = expf(lg);
        }
        int j = 0;
        for (; j + 8 <= n; j += 8) {
            float w8[8]; int s8[8]; float2 h8[8];
#pragma unroll
            for (int q = 0; q < 8; q++) {
                w8[q] = __shfl(wt, j + q, 64);
                s8[q] = __shfl(sp, j + q, 64);
            }
#pragma unroll
            for (int q = 0; q < 8; q++)
                h8[q] = ((const float2*)(h + (size_t)s8[q] * HIDDEN))[l];
#pragma unroll
            for (int q = 0; q < 8; q++) {
                acc.x += w8[q] * h8[q].x;
                acc.y += w8[q] * h8[q].y;
                wsum  += w8[q];
            }
        }
        for (; j + 4 <= n; j += 4) {
            float w4[4]; int s4[4]; float2 h4[4];
#pragma unroll
            for (int q = 0; q < 4; q++) {
                w4[q] = __shfl(wt, j + q, 64);
                s4[q] = __shfl(sp, j + q, 64);
            }
#pragma unroll
            for (int q = 0; q < 4; q++)
                h4[q] = ((const float2*)(h + (size_t)s4[q] * HIDDEN))[l];
#pragma unroll
            for (int q = 0; q < 4; q++) {
                acc.x += w4[q] * h4[q].x;
                acc.y += w4[q] * h4[q].y;
                wsum  += w4[q];
            }
        }
        for (; j < n; j++) {
            float w = __shfl(wt, j, 64);
            int   sj = __shfl(sp, j, 64);
            float2 hv = ((const float2*)(h + (size_t)sj * HIDDEN))[l];
            acc.x += w * hv.x;
            acc.y += w * hv.y;
            wsum  += w;
        }
    }
    float lg = alpha[i] + beta_i + selfc;
    lg = lg > 0.f ? lg : NEG * lg;
    float exi = expf(lg);
    float denom = wsum + exi + 1e-16f;
    float2 hv = ((const float2*)(h + (size_t)i * HIDDEN))[l];
    float2 bb = ((const float2*)b)[l];
    float bx = fmaxf((acc.x + exi * hv.x) / denom + bb.x, 0.f);
    float by = fmaxf((acc.y + exi * hv.y) / denom + bb.y, 0.f);
    // conv2 projections: B-row dot {va, vb, u}
    int c0 = 2 * l, c1 = 2 * l + 1;
    float pa2 = bx * consts[256 + c0] + by * consts[256 + c1];   // alpha2
    float pb2 = bx * consts[384 + c0] + by * consts[384 + c1];   // beta2
    float pgv = bx * consts[128 + c0] + by * consts[128 + c1];   // g
#pragma unroll
    for (int m = 32; m > 0; m >>= 1) {
        pa2 += __shfl_xor(pa2, m, 64);
        pb2 += __shfl_xor(pb2, m, 64);
        pgv += __shfl_xor(pgv, m, 64);
    }
    if (l == 0) {
        beta2[i] = pb2;
        pg[i] = make_float2(pa2, pgv);
    }
}

// ---------------------------------------------------------------------------
// agg2-lite: out[i] = relu((Σ w·g[src] + exi·g[i])/denom + bldot)
__global__ void __launch_bounds__(256)
agg2_lite_kernel(const int* __restrict__ off_work, const int* __restrict__ blockoff,
                 const int* __restrict__ count, const float4* __restrict__ erec,
                 const float2* __restrict__ pg, const float* __restrict__ beta2,
                 const float* __restrict__ part, const float* __restrict__ consts,
                 float* __restrict__ out) {
    int t = threadIdx.x, l = t & 63;
    int i = blockIdx.x * 4 + (t >> 6);
    float ps = part[l * 16 + 1];
#pragma unroll
    for (int m = 32; m > 0; m >>= 1) ps += __shfl_xor(ps, m, 64);
    float selfc = ps * (1.f / (float)N_EDGES);
    int start = off_work[i] + blockoff[i >> 8];
    int end   = start + count[i];
    float beta_i = beta2[i];
    float wsum = 0.f, gsum = 0.f;
    for (int e = start + l; e < end; e += 64) {
        float4 rec = erec[e];
        int sp = __float_as_int(rec.z);
        float2 ag = pg[sp];
        float lg = ag.x + beta_i + rec.y;
        lg = lg > 0.f ? lg : NEG * lg;
        float w = expf(lg);
        wsum += w;
        gsum += w * ag.y;
    }
    for (int m = 32; m > 0; m >>= 1) {
        wsum += __shfl_xor(wsum, m, 64);
        gsum += __shfl_xor(gsum, m, 64);
    }
    if (l == 0) {
        float2 agi = pg[i];
        float lg = agi.x + beta_i + selfc;
        lg = lg > 0.f ? lg : NEG * lg;
        float exi = expf(lg);
        float denom = wsum + exi + 1e-16f;
        out[i] = fmaxf((gsum + exi * agi.y) / denom + consts[64], 0.f);
    }
}

// ---------------------------------------------------------------------------
extern "C" void kernel_launch(void* const* d_in, const int* in_sizes, int n_in,
                              void* d_out, int out_size, void* d_ws, size_t ws_size,
                              hipStream_t stream) {
    const float* x   = (const float*)d_in[0];
    const int*   src = (const int*)  d_in[1];
    const int*   dst = (const int*)  d_in[2];
    const float* ea  = (const float*)d_in[3];
    const float* W1  = (const float*)d_in[4];
    const float* We1 = (const float*)d_in[5];
    const float* as1 = (const float*)d_in[6];
    const float* ad1 = (const float*)d_in[7];
    const float* ae1 = (const float*)d_in[8];
    const float* b1  = (const float*)d_in[9];
    const float* W2  = (const float*)d_in[10];
    const float* We2 = (const float*)d_in[11];
    const float* as2 = (const float*)d_in[12];
    const float* ad2 = (const float*)d_in[13];
    const float* ae2 = (const float*)d_in[14];
    const float* b2  = (const float*)d_in[15];
    const float* Wl  = (const float*)d_in[16];
    const float* bl  = (const float*)d_in[17];
    float* out = (float*)d_out;

    float* ws      = (float*)d_ws;
    float* A       = ws;                           // [N*128] h1
    float4* erec   = (float4*)(A + (size_t)N_NODES * HIDDEN);  // [E] packed
    unsigned short* whp1 = (unsigned short*)(erec + N_EDGES);
    unsigned short* wlp1 = whp1 + 16384;
    float* alpha1  = (float*)(wlp1 + 16384);       // [N]
    float* beta1   = alpha1 + N_NODES;             // [N]
    float* beta2   = beta1 + N_NODES;              // [N]
    float2* pg     = (float2*)(beta2 + N_NODES);   // [N] {alpha2, g}
    float* consts  = (float*)(pg + N_NODES);       // [512]
    float* part    = consts + 512;                 // [64*16]
    int* count     = (int*)(part + 64 * 16);       // [N]
    int* off_work  = count + N_NODES;              // [N]
    int* blocksum  = off_work + N_NODES;           // [SCAN_BLOCKS]
    int* blockoff  = blocksum + SCAN_BLOCKS;       // [SCAN_BLOCKS]
    int* rank      = blockoff + SCAN_BLOCKS;       // [E]

    // ---- prep ----
    hipMemsetAsync(count, 0, N_NODES * sizeof(int), stream);
    hipMemsetAsync(part, 0, 64 * 16 * sizeof(float), stream);
    fused_prep_kernel<<<EB + 66, 256, 0, stream>>>(dst, count, rank,
                                                   W1, whp1, wlp1,
                                                   We1, ae1, We2, ae2,
                                                   W2, as2, ad2, b2, Wl, bl,
                                                   consts);
    scan1_kernel<<<SCAN_BLOCKS, 256, 0, stream>>>(count, off_work, blocksum);
    scan2_kernel<<<1, 256, 0, stream>>>(blocksum, blockoff);

    // ---- scatter (edge records) + gemm1 (h1 -> A, alpha1/beta1) ----
    fused_scatter_gemm_kernel<<<EB + GEMM_BLOCKS, 256, 0, stream>>>(
        src, dst, rank, ea, consts, off_work, blockoff, erec, part,
        x, whp1, wlp1, as1, ad1, A, alpha1, beta1);

    // ---- conv1 aggregate + conv2-GEMM folded into epilogue ----
    agg1_kernel<<<N_NODES / 4, 256, 0, stream>>>(off_work, blockoff, count, erec,
                                                 A, alpha1, beta1, b1, part,
                                                 consts, beta2, pg);

    // ---- conv2 aggregate + final linear (scalar form) ----
    agg2_lite_kernel<<<N_NODES / 4, 256, 0, stream>>>(off_work, blockoff, count,
                                                      erec, pg, beta2, part,
                                                      consts, out);
}